// Round 9
// baseline (235.815 us; speedup 1.0000x reference)
//
#include <hip/hip_runtime.h>
#include <cstdint>
#include <cstddef>

#define S_DIM 1024
#define NPTS (S_DIM * S_DIM)
#define NLEV 16
#define TBL (1u << 19)
#define TMASK (TBL - 1u)
#define PRIME_Y 2654435761u

typedef float v2f __attribute__((ext_vector_type(2)));
typedef float v4f __attribute__((ext_vector_type(4)));
typedef short v8s __attribute__((ext_vector_type(8)));

static __device__ __forceinline__ v2f fma2(v2f a, v2f b, v2f c) {
    return __builtin_elementwise_fma(a, b, c);
}
static __device__ __forceinline__ v2f splat2(float s) { return (v2f){s, s}; }

// ---- split-bf16 helpers: x = hi + lo, both truncated bf16 ----
__device__ __forceinline__ void split2(float a, float b, uint32_t& hi, uint32_t& lo) {
    uint32_t ua = __float_as_uint(a), ub = __float_as_uint(b);
    uint32_t ha = ua & 0xFFFF0000u, hb = ub & 0xFFFF0000u;
    float la = a - __uint_as_float(ha);
    float lb = b - __uint_as_float(hb);
    hi = (ha >> 16) | hb;
    lo = (__float_as_uint(la) >> 16) | (__float_as_uint(lb) & 0xFFFF0000u);
}

// ============================================================================
// Pre-pass (verified round 5): bf16 hi/lo A-fragments of W0^T (64x32) and
// W1^T (64x64), fragment-linear in d_ws.
// ws as uint4: [0,256) W0hi | [256,512) W0lo | [512,1024) W1hi | [1024,1536) W1lo
// ============================================================================
__global__ __launch_bounds__(256) void prep_weights(const float* __restrict__ W0,
                                                    const float* __restrict__ W1,
                                                    uint4* __restrict__ ws) {
    const int tid = threadIdx.x;
    const int lane = tid & 63;
    const int m = lane & 15, q = lane >> 4;

    {   // W0^T
        const int tile = tid >> 6;
        const int n = tile * 16 + m;
        uint32_t hi[4], lo[4];
        #pragma unroll
        for (int d = 0; d < 4; ++d) {
            const int k0 = q * 8 + 2 * d;
            split2(W0[k0 * 64 + n], W0[(k0 + 1) * 64 + n], hi[d], lo[d]);
        }
        ws[tid]       = make_uint4(hi[0], hi[1], hi[2], hi[3]);
        ws[256 + tid] = make_uint4(lo[0], lo[1], lo[2], lo[3]);
    }

    #pragma unroll
    for (int rep = 0; rep < 2; ++rep) {   // W1^T
        const int unit = tid + rep * 256;
        const int l2 = unit & 63, frag = unit >> 6;
        const int nt = frag >> 1, ks = frag & 1;
        const int mm = l2 & 15, qq = l2 >> 4;
        const int n = nt * 16 + mm;
        uint32_t hi[4], lo[4];
        #pragma unroll
        for (int d = 0; d < 4; ++d) {
            const int k0 = ks * 32 + qq * 8 + 2 * d;
            split2(W1[k0 * 64 + n], W1[(k0 + 1) * 64 + n], hi[d], lo[d]);
        }
        ws[512 + unit]  = make_uint4(hi[0], hi[1], hi[2], hi[3]);
        ws[1024 + unit] = make_uint4(lo[0], lo[1], lo[2], lo[3]);
    }
}

// ---- pipeline stage 1: addresses + issue 4 gathers + frac weights ----
static __device__ __forceinline__ void level_issue(
    float x, float y, float fr, int st, bool dense, const float* __restrict__ tb,
    v2f& w, v2f& f00, v2f& f01, v2f& f10, v2f& f11)
{
    const float px = x * fr, py = y * fr;
    const float fx = floorf(px), fy = floorf(py);
    w = (v2f){px - fx, py - fy};
    const int x0 = (int)fx, y0 = (int)fy;

    const int d00 = x0 + y0 * st;
    const unsigned a = (unsigned)x0, b = (unsigned)y0;
    const unsigned hb0 = b * PRIME_Y, hb1 = hb0 + PRIME_Y;
    const int i00 = dense ? d00          : (int)((a ^ hb0) & TMASK);
    const int i01 = dense ? d00 + st     : (int)((a ^ hb1) & TMASK);
    const int i10 = dense ? d00 + 1      : (int)(((a + 1u) ^ hb0) & TMASK);
    const int i11 = dense ? d00 + st + 1 : (int)(((a + 1u) ^ hb1) & TMASK);

    f00 = *(const v2f*)(tb + 2 * (size_t)i00);
    f01 = *(const v2f*)(tb + 2 * (size_t)i01);
    f10 = *(const v2f*)(tb + 2 * (size_t)i10);
    f11 = *(const v2f*)(tb + 2 * (size_t)i11);
}

// ---- pipeline stage 2: packed bilinear interpolation ----
static __device__ __forceinline__ v2f interp2(v2f w, v2f f00, v2f f01, v2f f10, v2f f11) {
    const float omx = 1.f - w.x, omy = 1.f - w.y;
    const float w00 = omx * omy, w01 = omx * w.y, w10 = w.x * omy, w11 = w.x * w.y;
    v2f e = f00 * splat2(w00);
    e = fma2(f01, splat2(w01), e);
    e = fma2(f10, splat2(w10), e);
    e = fma2(f11, splat2(w11), e);
    return e;
}

// ============================================================================
// Main kernel. Block = 256 = 4 waves; each wave owns 64 points (4 tiles of 16).
// Direct-layout encoding (lane (q,m) encodes levels q*4..q*4+3 of point
// t*16+m). ROUND-9: 2-stage software pipeline across tiles -- tile t+1's 16
// table gathers are issued (into named loop-carried scalars; round-2 rule:
// no runtime-indexed arrays) before tile t's MFMA chain, hiding ~700 cyc of
// gather latency behind ~1200 cyc of compute. Round-8 counters: compute
// floor ~25 us vs 102 us observed => ~75 us exposed latency was the target.
// ============================================================================
__global__ __launch_bounds__(256, 2) void ngp_mfma(
    const float* __restrict__ xy,
    const float* __restrict__ tables,
    const float* __restrict__ W2,
    const uint4* __restrict__ ws,
    float* __restrict__ out)
{
    __shared__ uint4 w1LDS[1024];                       // 16384 B
    __shared__ alignas(16) uint32_t h0LDS[4 * 16 * 68]; // 17408 B
    __shared__ alignas(16) float w2t[3 * 64];           //   768 B

    const int tid = threadIdx.x;
    const int lane = tid & 63;
    const int wave = tid >> 6;
    const int m = lane & 15, q = lane >> 4;
    const int blockBase = blockIdx.x * 256;
    const int pbase = blockBase + wave * 64 + m;        // + t*16 per tile

    // ---- per-lane level constants: NAMED SCALARS (never an alloca) ----
    constexpr float RESF[NLEV] = {16.f, 24.f, 36.f, 54.f, 81.f, 121.f, 182.f, 273.f,
                                  410.f, 615.f, 922.f, 1383.f, 2075.f, 3113.f, 4670.f, 7006.f};
#define LVLF(i) ((q & 2) ? ((q & 1) ? RESF[12 + (i)] : RESF[8 + (i)]) \
                         : ((q & 1) ? RESF[4 + (i)]  : RESF[(i)]))
    const float fr0 = LVLF(0), fr1 = LVLF(1), fr2 = LVLF(2), fr3 = LVLF(3);
#undef LVLF
    const int st0 = (int)fr0 + 1, st1 = (int)fr1 + 1;
    const int st2 = (int)fr2 + 1, st3 = (int)fr3 + 1;
    const bool dn0 = (q <= 2), dn1 = (q <= 2), dn2 = (q <= 1), dn3 = (q <= 1);
    const float* tb0 = tables + ((size_t)(unsigned)(q * 4 + 0) << 20);
    const float* tb1 = tables + ((size_t)(unsigned)(q * 4 + 1) << 20);
    const float* tb2 = tables + ((size_t)(unsigned)(q * 4 + 2) << 20);
    const float* tb3 = tables + ((size_t)(unsigned)(q * 4 + 3) << 20);

    // ---- pipeline prologue: issue tile 0's gathers ----
    v2f cw0, cw1, cw2, cw3;
    v2f c0a, c0b, c0c, c0d, c1a, c1b, c1c, c1d;
    v2f c2a, c2b, c2c, c2d, c3a, c3b, c3c, c3d;
    {
        const float2 p = ((const float2*)xy)[pbase];
        level_issue(p.x, p.y, fr0, st0, dn0, tb0, cw0, c0a, c0b, c0c, c0d);
        level_issue(p.x, p.y, fr1, st1, dn1, tb1, cw1, c1a, c1b, c1c, c1d);
        level_issue(p.x, p.y, fr2, st2, dn2, tb2, cw2, c2a, c2b, c2c, c2d);
        level_issue(p.x, p.y, fr3, st3, dn3, tb3, cw3, c3a, c3b, c3c, c3d);
    }

    // ---- stage W1 frags + W2^T into LDS (covers tile-0 gather latency) ----
    #pragma unroll
    for (int r = 0; r < 4; ++r) w1LDS[r * 256 + tid] = ws[512 + r * 256 + tid];
    if (tid < 192) w2t[(tid % 3) * 64 + (tid / 3)] = W2[tid];

    // ---- W0 frags resident (reused all 4 tiles) ----
    v8s w0h[4], w0l[4];
    #pragma unroll
    for (int t4 = 0; t4 < 4; ++t4) {
        w0h[t4] = __builtin_bit_cast(v8s, ws[t4 * 64 + lane]);
        w0l[t4] = __builtin_bit_cast(v8s, ws[256 + t4 * 64 + lane]);
    }

    __syncthreads();   // w1LDS + w2t visibility

    #pragma unroll 1
    for (int t = 0; t < 4; ++t) {
        // ---- issue tile t+1's gathers FIRST (latency hidden by tile t) ----
        v2f nw0, nw1, nw2, nw3;
        v2f n0a, n0b, n0c, n0d, n1a, n1b, n1c, n1d;
        v2f n2a, n2b, n2c, n2d, n3a, n3b, n3c, n3d;
        if (t < 3) {
            const float2 pn = ((const float2*)xy)[pbase + (t + 1) * 16];
            level_issue(pn.x, pn.y, fr0, st0, dn0, tb0, nw0, n0a, n0b, n0c, n0d);
            level_issue(pn.x, pn.y, fr1, st1, dn1, tb1, nw1, n1a, n1b, n1c, n1d);
            level_issue(pn.x, pn.y, fr2, st2, dn2, tb2, nw2, n2a, n2b, n2c, n2d);
            level_issue(pn.x, pn.y, fr3, st3, dn3, tb3, nw3, n3a, n3b, n3c, n3d);
        }

        // ---- interpolate tile t (gathers issued last iteration) ----
        const v2f e0 = interp2(cw0, c0a, c0b, c0c, c0d);
        const v2f e1 = interp2(cw1, c1a, c1b, c1c, c1d);
        const v2f e2 = interp2(cw2, c2a, c2b, c2c, c2d);
        const v2f e3 = interp2(cw3, c3a, c3b, c3c, c3d);
        uint32_t eh0, el0, eh1, el1, eh2, el2, eh3, el3;
        split2(e0.x, e0.y, eh0, el0);
        split2(e1.x, e1.y, eh1, el1);
        split2(e2.x, e2.y, eh2, el2);
        split2(e3.x, e3.y, eh3, el3);
        const v8s eH = __builtin_bit_cast(v8s, make_uint4(eh0, eh1, eh2, eh3));
        const v8s eL = __builtin_bit_cast(v8s, make_uint4(el0, el1, el2, el3));

        // ---- L0: D0[n][p] = W0^T x enc^T, 3-term split ----
        v4f acc0[4];
        #pragma unroll
        for (int nt = 0; nt < 4; ++nt) {
            v4f c = {0.f, 0.f, 0.f, 0.f};
            c = __builtin_amdgcn_mfma_f32_16x16x32_bf16(w0l[nt], eH, c, 0, 0, 0);
            c = __builtin_amdgcn_mfma_f32_16x16x32_bf16(w0h[nt], eL, c, 0, 0, 0);
            c = __builtin_amdgcn_mfma_f32_16x16x32_bf16(w0h[nt], eH, c, 0, 0, 0);
            acc0[nt] = c;
        }

        // ---- relu + split h0 -> wave-local LDS bounce (C-layout -> B-layout)
        uint32_t* hrow = h0LDS + (wave * 16 + m) * 68;
        #pragma unroll
        for (int nt = 0; nt < 4; ++nt) {
            const float r0 = fmaxf(acc0[nt][0], 0.f), r1 = fmaxf(acc0[nt][1], 0.f);
            const float r2 = fmaxf(acc0[nt][2], 0.f), r3 = fmaxf(acc0[nt][3], 0.f);
            uint32_t h0w, l0w, h1w, l1w;
            split2(r0, r1, h0w, l0w);
            split2(r2, r3, h1w, l1w);
            *((uint2*)(hrow + nt * 8 + q * 2))      = make_uint2(h0w, h1w);
            *((uint2*)(hrow + 32 + nt * 8 + q * 2)) = make_uint2(l0w, l1w);
        }

        // ---- L1 B-frags ----
        const v8s b0H = __builtin_bit_cast(v8s, *((const uint4*)(hrow + q * 4)));
        const v8s b0L = __builtin_bit_cast(v8s, *((const uint4*)(hrow + 32 + q * 4)));
        const v8s b1H = __builtin_bit_cast(v8s, *((const uint4*)(hrow + 16 + q * 4)));
        const v8s b1L = __builtin_bit_cast(v8s, *((const uint4*)(hrow + 48 + q * 4)));

        // ---- L1 + L2 epilogue fused per n-tile ----
        float o0 = 0.f, o1 = 0.f, o2 = 0.f;
        #pragma unroll
        for (int nt = 0; nt < 4; ++nt) {
            const v8s a0h = __builtin_bit_cast(v8s, w1LDS[(nt * 2 + 0) * 64 + lane]);
            const v8s a0l = __builtin_bit_cast(v8s, w1LDS[512 + (nt * 2 + 0) * 64 + lane]);
            const v8s a1h = __builtin_bit_cast(v8s, w1LDS[(nt * 2 + 1) * 64 + lane]);
            const v8s a1l = __builtin_bit_cast(v8s, w1LDS[512 + (nt * 2 + 1) * 64 + lane]);
            v4f c = {0.f, 0.f, 0.f, 0.f};
            c = __builtin_amdgcn_mfma_f32_16x16x32_bf16(a0l, b0H, c, 0, 0, 0);
            c = __builtin_amdgcn_mfma_f32_16x16x32_bf16(a0h, b0L, c, 0, 0, 0);
            c = __builtin_amdgcn_mfma_f32_16x16x32_bf16(a0h, b0H, c, 0, 0, 0);
            c = __builtin_amdgcn_mfma_f32_16x16x32_bf16(a1l, b1H, c, 0, 0, 0);
            c = __builtin_amdgcn_mfma_f32_16x16x32_bf16(a1h, b1L, c, 0, 0, 0);
            c = __builtin_amdgcn_mfma_f32_16x16x32_bf16(a1h, b1H, c, 0, 0, 0);

            const int n = nt * 16 + q * 4;
            const float4 wa = *((const float4*)(w2t + 0 * 64 + n));
            const float4 wb = *((const float4*)(w2t + 1 * 64 + n));
            const float4 wc = *((const float4*)(w2t + 2 * 64 + n));
            const float h0r = fmaxf(c[0], 0.f), h1r = fmaxf(c[1], 0.f);
            const float h2r = fmaxf(c[2], 0.f), h3r = fmaxf(c[3], 0.f);
            o0 = fmaf(h0r, wa.x, fmaf(h1r, wa.y, fmaf(h2r, wa.z, fmaf(h3r, wa.w, o0))));
            o1 = fmaf(h0r, wb.x, fmaf(h1r, wb.y, fmaf(h2r, wb.z, fmaf(h3r, wb.w, o1))));
            o2 = fmaf(h0r, wc.x, fmaf(h1r, wc.y, fmaf(h2r, wc.z, fmaf(h3r, wc.w, o2))));
        }

        o0 += __shfl_xor(o0, 16); o0 += __shfl_xor(o0, 32);
        o1 += __shfl_xor(o1, 16); o1 += __shfl_xor(o1, 32);
        o2 += __shfl_xor(o2, 16); o2 += __shfl_xor(o2, 32);

        if (lane < 16) {
            const int pidx = blockBase + wave * 64 + t * 16 + lane;
            out[pidx] = o0;
            out[NPTS + pidx] = o1;
            out[2 * NPTS + pidx] = o2;
        }

        // ---- rotate pipeline state ----
        if (t < 3) {
            cw0 = nw0; cw1 = nw1; cw2 = nw2; cw3 = nw3;
            c0a = n0a; c0b = n0b; c0c = n0c; c0d = n0d;
            c1a = n1a; c1b = n1b; c1c = n1c; c1d = n1d;
            c2a = n2a; c2b = n2b; c2c = n2c; c2d = n2d;
            c3a = n3a; c3b = n3b; c3c = n3c; c3d = n3d;
        }
    }
}

extern "C" void kernel_launch(void* const* d_in, const int* in_sizes, int n_in,
                              void* d_out, int out_size, void* d_ws, size_t ws_size,
                              hipStream_t stream) {
    const float* xy     = (const float*)d_in[0];
    const float* tables = (const float*)d_in[1];
    const float* W0     = (const float*)d_in[2];
    const float* W1     = (const float*)d_in[3];
    const float* W2     = (const float*)d_in[4];
    float* out = (float*)d_out;
    uint4* ws  = (uint4*)d_ws;   // 1536 x 16B = 24 KB

    hipLaunchKernelGGL(prep_weights, dim3(1), dim3(256), 0, stream, W0, W1, ws);
    hipLaunchKernelGGL(ngp_mfma, dim3(NPTS / 256), dim3(256), 0, stream,
                       xy, tables, W2, ws, out);
}

// Round 10
// 214.758 us; speedup vs baseline: 1.0980x; 1.0980x over previous
//
#include <hip/hip_runtime.h>
#include <cstdint>
#include <cstddef>

#define S_DIM 1024
#define NPTS (S_DIM * S_DIM)
#define NLEV 16
#define TBL (1u << 19)
#define TMASK (TBL - 1u)
#define PRIME_Y 2654435761u

typedef float v2f __attribute__((ext_vector_type(2)));
typedef float v4f __attribute__((ext_vector_type(4)));
typedef short v8s __attribute__((ext_vector_type(8)));

static __device__ __forceinline__ v2f fma2(v2f a, v2f b, v2f c) {
    return __builtin_elementwise_fma(a, b, c);
}
static __device__ __forceinline__ v2f splat2(float s) { return (v2f){s, s}; }

// ---- split-bf16 helpers: x = hi + lo, both truncated bf16 ----
__device__ __forceinline__ void split2(float a, float b, uint32_t& hi, uint32_t& lo) {
    uint32_t ua = __float_as_uint(a), ub = __float_as_uint(b);
    uint32_t ha = ua & 0xFFFF0000u, hb = ub & 0xFFFF0000u;
    float la = a - __uint_as_float(ha);
    float lb = b - __uint_as_float(hb);
    hi = (ha >> 16) | hb;
    lo = (__float_as_uint(la) >> 16) | (__float_as_uint(lb) & 0xFFFF0000u);
}

// ============================================================================
// Pre-pass (verified round 5): bf16 hi/lo A-fragments of W0^T (64x32) and
// W1^T (64x64), fragment-linear in d_ws.
// ws as uint4: [0,256) W0hi | [256,512) W0lo | [512,1024) W1hi | [1024,1536) W1lo
// ============================================================================
__global__ __launch_bounds__(256) void prep_weights(const float* __restrict__ W0,
                                                    const float* __restrict__ W1,
                                                    uint4* __restrict__ ws) {
    const int tid = threadIdx.x;
    const int lane = tid & 63;
    const int m = lane & 15, q = lane >> 4;

    {   // W0^T
        const int tile = tid >> 6;
        const int n = tile * 16 + m;
        uint32_t hi[4], lo[4];
        #pragma unroll
        for (int d = 0; d < 4; ++d) {
            const int k0 = q * 8 + 2 * d;
            split2(W0[k0 * 64 + n], W0[(k0 + 1) * 64 + n], hi[d], lo[d]);
        }
        ws[tid]       = make_uint4(hi[0], hi[1], hi[2], hi[3]);
        ws[256 + tid] = make_uint4(lo[0], lo[1], lo[2], lo[3]);
    }

    #pragma unroll
    for (int rep = 0; rep < 2; ++rep) {   // W1^T
        const int unit = tid + rep * 256;
        const int l2 = unit & 63, frag = unit >> 6;
        const int nt = frag >> 1, ks = frag & 1;
        const int mm = l2 & 15, qq = l2 >> 4;
        const int n = nt * 16 + mm;
        uint32_t hi[4], lo[4];
        #pragma unroll
        for (int d = 0; d < 4; ++d) {
            const int k0 = ks * 32 + qq * 8 + 2 * d;
            split2(W1[k0 * 64 + n], W1[(k0 + 1) * 64 + n], hi[d], lo[d]);
        }
        ws[512 + unit]  = make_uint4(hi[0], hi[1], hi[2], hi[3]);
        ws[1024 + unit] = make_uint4(lo[0], lo[1], lo[2], lo[3]);
    }
}

// W2 (64x3) -> w2tG[c][n] (3x64) for the split path's epilogue.
__global__ __launch_bounds__(256) void prep_w2t(const float* __restrict__ W2,
                                                float* __restrict__ w2tG) {
    const int tid = threadIdx.x;
    if (tid < 192) w2tG[(tid % 3) * 64 + (tid / 3)] = W2[tid];
}

// ---- per-level hash-grid feature, runtime level constants (branchless) ----
static __device__ __forceinline__ float2 level_feat_rt(float x, float y, float fr,
                                                       int st /*res+1*/, bool dense,
                                                       const float* __restrict__ tb) {
    const float px = x * fr, py = y * fr;
    const float fx = floorf(px), fy = floorf(py);
    const float wx = px - fx, wy = py - fy;
    const int x0 = (int)fx, y0 = (int)fy;

    const int d00 = x0 + y0 * st;
    const unsigned a = (unsigned)x0, b = (unsigned)y0;
    const unsigned hb0 = b * PRIME_Y, hb1 = hb0 + PRIME_Y;
    const int i00 = dense ? d00          : (int)((a ^ hb0) & TMASK);
    const int i01 = dense ? d00 + st     : (int)((a ^ hb1) & TMASK);
    const int i10 = dense ? d00 + 1      : (int)(((a + 1u) ^ hb0) & TMASK);
    const int i11 = dense ? d00 + st + 1 : (int)(((a + 1u) ^ hb1) & TMASK);

    const float2 f00 = *(const float2*)(tb + 2 * (size_t)i00);
    const float2 f01 = *(const float2*)(tb + 2 * (size_t)i01);
    const float2 f10 = *(const float2*)(tb + 2 * (size_t)i10);
    const float2 f11 = *(const float2*)(tb + 2 * (size_t)i11);

    const float omx = 1.f - wx, omy = 1.f - wy;
    const float w00 = omx * omy, w01 = omx * wy, w10 = wx * omy, w11 = wx * wy;

    float2 e;
    e.x = f00.x * w00 + f01.x * w01 + f10.x * w10 + f11.x * w11;
    e.y = f00.y * w00 + f01.y * w01 + f10.y * w10 + f11.y * w11;
    return e;
}

// ============================================================================
// SPLIT KERNEL A: encode. 4 lanes per point (one per level group q), writing
// enc hi/lo directly in MFMA B-frag order: encHi[tile*64 + q*16 + m].
// Tiny register footprint + zero LDS -> 8 waves/EU of TLP to saturate the
// TA/L2 gather path (the round-8 bottleneck analysis: ~47 us TA floor).
// ============================================================================
__global__ __launch_bounds__(256) void ngp_encode(
    const float* __restrict__ xy,
    const float* __restrict__ tables,
    uint4* __restrict__ encHi,
    uint4* __restrict__ encLo)
{
    const int tid = threadIdx.x;
    const int q = tid >> 6;            // wave index = level group (wave-uniform)
    const int pl = tid & 63;
    const int p = blockIdx.x * 64 + pl;

    constexpr float RESF[NLEV] = {16.f, 24.f, 36.f, 54.f, 81.f, 121.f, 182.f, 273.f,
                                  410.f, 615.f, 922.f, 1383.f, 2075.f, 3113.f, 4670.f, 7006.f};
#define LVLF(i) ((q & 2) ? ((q & 1) ? RESF[12 + (i)] : RESF[8 + (i)]) \
                         : ((q & 1) ? RESF[4 + (i)]  : RESF[(i)]))
    const float fr0 = LVLF(0), fr1 = LVLF(1), fr2 = LVLF(2), fr3 = LVLF(3);
#undef LVLF
    const int st0 = (int)fr0 + 1, st1 = (int)fr1 + 1;
    const int st2 = (int)fr2 + 1, st3 = (int)fr3 + 1;
    const bool dn0 = (q <= 2), dn1 = (q <= 2), dn2 = (q <= 1), dn3 = (q <= 1);
    const float* tb0 = tables + ((size_t)(unsigned)(q * 4 + 0) << 20);
    const float* tb1 = tables + ((size_t)(unsigned)(q * 4 + 1) << 20);
    const float* tb2 = tables + ((size_t)(unsigned)(q * 4 + 2) << 20);
    const float* tb3 = tables + ((size_t)(unsigned)(q * 4 + 3) << 20);

    const float2 pt = ((const float2*)xy)[p];
    const float2 e0 = level_feat_rt(pt.x, pt.y, fr0, st0, dn0, tb0);
    const float2 e1 = level_feat_rt(pt.x, pt.y, fr1, st1, dn1, tb1);
    const float2 e2 = level_feat_rt(pt.x, pt.y, fr2, st2, dn2, tb2);
    const float2 e3 = level_feat_rt(pt.x, pt.y, fr3, st3, dn3, tb3);

    uint32_t eh0, el0, eh1, el1, eh2, el2, eh3, el3;
    split2(e0.x, e0.y, eh0, el0);
    split2(e1.x, e1.y, eh1, el1);
    split2(e2.x, e2.y, eh2, el2);
    split2(e3.x, e3.y, eh3, el3);

    const int idx = blockIdx.x * 256 + (pl >> 4) * 64 + q * 16 + (pl & 15);
    encHi[idx] = make_uint4(eh0, eh1, eh2, eh3);
    encLo[idx] = make_uint4(el0, el1, el2, el3);
}

// ============================================================================
// SPLIT KERNEL B: pure MFMA MLP (round-8 phase 2 verbatim). enc read is one
// coalesced uint4/lane/tile with depth-1 prefetch (8 regs). W1/W2 frags read
// from global (L1-hot 25 KB); only h0LDS remains (17.4 KB) and it is
// wave-local -> NO barriers.
// ============================================================================
__global__ __launch_bounds__(256, 2) void ngp_mlp(
    const uint4* __restrict__ ws,
    const uint4* __restrict__ encHi,
    const uint4* __restrict__ encLo,
    const float* __restrict__ w2tG,
    float* __restrict__ out)
{
    __shared__ alignas(16) uint32_t h0LDS[4 * 16 * 68]; // 17408 B

    const int tid = threadIdx.x;
    const int lane = tid & 63;
    const int wave = tid >> 6;
    const int m = lane & 15, q = lane >> 4;
    const int blockBase = blockIdx.x * 256;
    const int tileBase = blockIdx.x * 16 + wave * 4;

    // ---- W0 frags resident ----
    v8s w0h[4], w0l[4];
    #pragma unroll
    for (int t4 = 0; t4 < 4; ++t4) {
        w0h[t4] = __builtin_bit_cast(v8s, ws[t4 * 64 + lane]);
        w0l[t4] = __builtin_bit_cast(v8s, ws[256 + t4 * 64 + lane]);
    }

    // ---- prologue: load tile 0's enc frags ----
    uint4 cH = encHi[tileBase * 64 + lane];
    uint4 cL = encLo[tileBase * 64 + lane];

    #pragma unroll 1
    for (int t = 0; t < 4; ++t) {
        // depth-1 prefetch of next tile's enc (clamped; 8 regs only)
        const int tn = (t < 3) ? (t + 1) : 3;
        const uint4 nH = encHi[(tileBase + tn) * 64 + lane];
        const uint4 nL = encLo[(tileBase + tn) * 64 + lane];

        const v8s eH = __builtin_bit_cast(v8s, cH);
        const v8s eL = __builtin_bit_cast(v8s, cL);

        // ---- L0: D0[n][p] = W0^T x enc^T, 3-term split ----
        v4f acc0[4];
        #pragma unroll
        for (int nt = 0; nt < 4; ++nt) {
            v4f c = {0.f, 0.f, 0.f, 0.f};
            c = __builtin_amdgcn_mfma_f32_16x16x32_bf16(w0l[nt], eH, c, 0, 0, 0);
            c = __builtin_amdgcn_mfma_f32_16x16x32_bf16(w0h[nt], eL, c, 0, 0, 0);
            c = __builtin_amdgcn_mfma_f32_16x16x32_bf16(w0h[nt], eH, c, 0, 0, 0);
            acc0[nt] = c;
        }

        // ---- relu + split h0 -> wave-local LDS bounce ----
        uint32_t* hrow = h0LDS + (wave * 16 + m) * 68;
        #pragma unroll
        for (int nt = 0; nt < 4; ++nt) {
            const float r0 = fmaxf(acc0[nt][0], 0.f), r1 = fmaxf(acc0[nt][1], 0.f);
            const float r2 = fmaxf(acc0[nt][2], 0.f), r3 = fmaxf(acc0[nt][3], 0.f);
            uint32_t h0w, l0w, h1w, l1w;
            split2(r0, r1, h0w, l0w);
            split2(r2, r3, h1w, l1w);
            *((uint2*)(hrow + nt * 8 + q * 2))      = make_uint2(h0w, h1w);
            *((uint2*)(hrow + 32 + nt * 8 + q * 2)) = make_uint2(l0w, l1w);
        }

        // ---- L1 B-frags ----
        const v8s b0H = __builtin_bit_cast(v8s, *((const uint4*)(hrow + q * 4)));
        const v8s b0L = __builtin_bit_cast(v8s, *((const uint4*)(hrow + 32 + q * 4)));
        const v8s b1H = __builtin_bit_cast(v8s, *((const uint4*)(hrow + 16 + q * 4)));
        const v8s b1L = __builtin_bit_cast(v8s, *((const uint4*)(hrow + 48 + q * 4)));

        // ---- L1 + L2 epilogue fused per n-tile (W1 frags from global, L1-hot)
        float o0 = 0.f, o1 = 0.f, o2 = 0.f;
        #pragma unroll
        for (int nt = 0; nt < 4; ++nt) {
            const v8s a0h = __builtin_bit_cast(v8s, ws[512 + (nt * 2 + 0) * 64 + lane]);
            const v8s a0l = __builtin_bit_cast(v8s, ws[1024 + (nt * 2 + 0) * 64 + lane]);
            const v8s a1h = __builtin_bit_cast(v8s, ws[512 + (nt * 2 + 1) * 64 + lane]);
            const v8s a1l = __builtin_bit_cast(v8s, ws[1024 + (nt * 2 + 1) * 64 + lane]);
            v4f c = {0.f, 0.f, 0.f, 0.f};
            c = __builtin_amdgcn_mfma_f32_16x16x32_bf16(a0l, b0H, c, 0, 0, 0);
            c = __builtin_amdgcn_mfma_f32_16x16x32_bf16(a0h, b0L, c, 0, 0, 0);
            c = __builtin_amdgcn_mfma_f32_16x16x32_bf16(a0h, b0H, c, 0, 0, 0);
            c = __builtin_amdgcn_mfma_f32_16x16x32_bf16(a1l, b1H, c, 0, 0, 0);
            c = __builtin_amdgcn_mfma_f32_16x16x32_bf16(a1h, b1L, c, 0, 0, 0);
            c = __builtin_amdgcn_mfma_f32_16x16x32_bf16(a1h, b1H, c, 0, 0, 0);

            const int n = nt * 16 + q * 4;
            const float4 wa = *((const float4*)(w2tG + 0 * 64 + n));
            const float4 wb = *((const float4*)(w2tG + 1 * 64 + n));
            const float4 wc = *((const float4*)(w2tG + 2 * 64 + n));
            const float h0r = fmaxf(c[0], 0.f), h1r = fmaxf(c[1], 0.f);
            const float h2r = fmaxf(c[2], 0.f), h3r = fmaxf(c[3], 0.f);
            o0 = fmaf(h0r, wa.x, fmaf(h1r, wa.y, fmaf(h2r, wa.z, fmaf(h3r, wa.w, o0))));
            o1 = fmaf(h0r, wb.x, fmaf(h1r, wb.y, fmaf(h2r, wb.z, fmaf(h3r, wb.w, o1))));
            o2 = fmaf(h0r, wc.x, fmaf(h1r, wc.y, fmaf(h2r, wc.z, fmaf(h3r, wc.w, o2))));
        }

        o0 += __shfl_xor(o0, 16); o0 += __shfl_xor(o0, 32);
        o1 += __shfl_xor(o1, 16); o1 += __shfl_xor(o1, 32);
        o2 += __shfl_xor(o2, 16); o2 += __shfl_xor(o2, 32);

        if (lane < 16) {
            const int pidx = blockBase + wave * 64 + t * 16 + lane;
            out[pidx] = o0;
            out[NPTS + pidx] = o1;
            out[2 * NPTS + pidx] = o2;
        }

        cH = nH; cL = nL;
    }
}

// ============================================================================
// FALLBACK (ws too small): round-8 fused kernel, verbatim (102 us known-good).
// ============================================================================
__global__ __launch_bounds__(256, 2) void ngp_mfma(
    const float* __restrict__ xy,
    const float* __restrict__ tables,
    const float* __restrict__ W2,
    const uint4* __restrict__ ws,
    float* __restrict__ out)
{
    __shared__ uint4 w1LDS[1024];
    __shared__ alignas(16) uint32_t h0LDS[4 * 16 * 68];
    __shared__ alignas(16) float w2t[3 * 64];

    const int tid = threadIdx.x;
    const int lane = tid & 63;
    const int wave = tid >> 6;
    const int m = lane & 15, q = lane >> 4;
    const int blockBase = blockIdx.x * 256;
    const int pbase = blockBase + wave * 64 + m;

    #pragma unroll
    for (int r = 0; r < 4; ++r) w1LDS[r * 256 + tid] = ws[512 + r * 256 + tid];
    if (tid < 192) w2t[(tid % 3) * 64 + (tid / 3)] = W2[tid];

    v8s w0h[4], w0l[4];
    #pragma unroll
    for (int t4 = 0; t4 < 4; ++t4) {
        w0h[t4] = __builtin_bit_cast(v8s, ws[t4 * 64 + lane]);
        w0l[t4] = __builtin_bit_cast(v8s, ws[256 + t4 * 64 + lane]);
    }

    constexpr float RESF[NLEV] = {16.f, 24.f, 36.f, 54.f, 81.f, 121.f, 182.f, 273.f,
                                  410.f, 615.f, 922.f, 1383.f, 2075.f, 3113.f, 4670.f, 7006.f};
#define LVLF(i) ((q & 2) ? ((q & 1) ? RESF[12 + (i)] : RESF[8 + (i)]) \
                         : ((q & 1) ? RESF[4 + (i)]  : RESF[(i)]))
    const float fr0 = LVLF(0), fr1 = LVLF(1), fr2 = LVLF(2), fr3 = LVLF(3);
#undef LVLF
    const int st0 = (int)fr0 + 1, st1 = (int)fr1 + 1;
    const int st2 = (int)fr2 + 1, st3 = (int)fr3 + 1;
    const bool dn0 = (q <= 2), dn1 = (q <= 2), dn2 = (q <= 1), dn3 = (q <= 1);
    const float* tb0 = tables + ((size_t)(unsigned)(q * 4 + 0) << 20);
    const float* tb1 = tables + ((size_t)(unsigned)(q * 4 + 1) << 20);
    const float* tb2 = tables + ((size_t)(unsigned)(q * 4 + 2) << 20);
    const float* tb3 = tables + ((size_t)(unsigned)(q * 4 + 3) << 20);

    __syncthreads();

    #pragma unroll 1
    for (int t = 0; t < 4; ++t) {
        const float2 p = ((const float2*)xy)[pbase + t * 16];
        const float2 e0 = level_feat_rt(p.x, p.y, fr0, st0, dn0, tb0);
        const float2 e1 = level_feat_rt(p.x, p.y, fr1, st1, dn1, tb1);
        const float2 e2 = level_feat_rt(p.x, p.y, fr2, st2, dn2, tb2);
        const float2 e3 = level_feat_rt(p.x, p.y, fr3, st3, dn3, tb3);
        uint32_t eh0, el0, eh1, el1, eh2, el2, eh3, el3;
        split2(e0.x, e0.y, eh0, el0);
        split2(e1.x, e1.y, eh1, el1);
        split2(e2.x, e2.y, eh2, el2);
        split2(e3.x, e3.y, eh3, el3);
        const v8s eH = __builtin_bit_cast(v8s, make_uint4(eh0, eh1, eh2, eh3));
        const v8s eL = __builtin_bit_cast(v8s, make_uint4(el0, el1, el2, el3));

        v4f acc0[4];
        #pragma unroll
        for (int nt = 0; nt < 4; ++nt) {
            v4f c = {0.f, 0.f, 0.f, 0.f};
            c = __builtin_amdgcn_mfma_f32_16x16x32_bf16(w0l[nt], eH, c, 0, 0, 0);
            c = __builtin_amdgcn_mfma_f32_16x16x32_bf16(w0h[nt], eL, c, 0, 0, 0);
            c = __builtin_amdgcn_mfma_f32_16x16x32_bf16(w0h[nt], eH, c, 0, 0, 0);
            acc0[nt] = c;
        }

        uint32_t* hrow = h0LDS + (wave * 16 + m) * 68;
        #pragma unroll
        for (int nt = 0; nt < 4; ++nt) {
            const float r0 = fmaxf(acc0[nt][0], 0.f), r1 = fmaxf(acc0[nt][1], 0.f);
            const float r2 = fmaxf(acc0[nt][2], 0.f), r3 = fmaxf(acc0[nt][3], 0.f);
            uint32_t h0w, l0w, h1w, l1w;
            split2(r0, r1, h0w, l0w);
            split2(r2, r3, h1w, l1w);
            *((uint2*)(hrow + nt * 8 + q * 2))      = make_uint2(h0w, h1w);
            *((uint2*)(hrow + 32 + nt * 8 + q * 2)) = make_uint2(l0w, l1w);
        }

        const v8s b0H = __builtin_bit_cast(v8s, *((const uint4*)(hrow + q * 4)));
        const v8s b0L = __builtin_bit_cast(v8s, *((const uint4*)(hrow + 32 + q * 4)));
        const v8s b1H = __builtin_bit_cast(v8s, *((const uint4*)(hrow + 16 + q * 4)));
        const v8s b1L = __builtin_bit_cast(v8s, *((const uint4*)(hrow + 48 + q * 4)));

        float o0 = 0.f, o1 = 0.f, o2 = 0.f;
        #pragma unroll
        for (int nt = 0; nt < 4; ++nt) {
            const v8s a0h = __builtin_bit_cast(v8s, w1LDS[(nt * 2 + 0) * 64 + lane]);
            const v8s a0l = __builtin_bit_cast(v8s, w1LDS[512 + (nt * 2 + 0) * 64 + lane]);
            const v8s a1h = __builtin_bit_cast(v8s, w1LDS[(nt * 2 + 1) * 64 + lane]);
            const v8s a1l = __builtin_bit_cast(v8s, w1LDS[512 + (nt * 2 + 1) * 64 + lane]);
            v4f c = {0.f, 0.f, 0.f, 0.f};
            c = __builtin_amdgcn_mfma_f32_16x16x32_bf16(a0l, b0H, c, 0, 0, 0);
            c = __builtin_amdgcn_mfma_f32_16x16x32_bf16(a0h, b0L, c, 0, 0, 0);
            c = __builtin_amdgcn_mfma_f32_16x16x32_bf16(a0h, b0H, c, 0, 0, 0);
            c = __builtin_amdgcn_mfma_f32_16x16x32_bf16(a1l, b1H, c, 0, 0, 0);
            c = __builtin_amdgcn_mfma_f32_16x16x32_bf16(a1h, b1L, c, 0, 0, 0);
            c = __builtin_amdgcn_mfma_f32_16x16x32_bf16(a1h, b1H, c, 0, 0, 0);

            const int n = nt * 16 + q * 4;
            const float4 wa = *((const float4*)(w2t + 0 * 64 + n));
            const float4 wb = *((const float4*)(w2t + 1 * 64 + n));
            const float4 wc = *((const float4*)(w2t + 2 * 64 + n));
            const float h0r = fmaxf(c[0], 0.f), h1r = fmaxf(c[1], 0.f);
            const float h2r = fmaxf(c[2], 0.f), h3r = fmaxf(c[3], 0.f);
            o0 = fmaf(h0r, wa.x, fmaf(h1r, wa.y, fmaf(h2r, wa.z, fmaf(h3r, wa.w, o0))));
            o1 = fmaf(h0r, wb.x, fmaf(h1r, wb.y, fmaf(h2r, wb.z, fmaf(h3r, wb.w, o1))));
            o2 = fmaf(h0r, wc.x, fmaf(h1r, wc.y, fmaf(h2r, wc.z, fmaf(h3r, wc.w, o2))));
        }

        o0 += __shfl_xor(o0, 16); o0 += __shfl_xor(o0, 32);
        o1 += __shfl_xor(o1, 16); o1 += __shfl_xor(o1, 32);
        o2 += __shfl_xor(o2, 16); o2 += __shfl_xor(o2, 32);

        if (lane < 16) {
            const int pidx = blockBase + wave * 64 + t * 16 + lane;
            out[pidx] = o0;
            out[NPTS + pidx] = o1;
            out[2 * NPTS + pidx] = o2;
        }
    }
}

extern "C" void kernel_launch(void* const* d_in, const int* in_sizes, int n_in,
                              void* d_out, int out_size, void* d_ws, size_t ws_size,
                              hipStream_t stream) {
    const float* xy     = (const float*)d_in[0];
    const float* tables = (const float*)d_in[1];
    const float* W0     = (const float*)d_in[2];
    const float* W1     = (const float*)d_in[3];
    const float* W2     = (const float*)d_in[4];
    float* out = (float*)d_out;
    uint4* ws  = (uint4*)d_ws;

    // layout: [0,24576) weight frags | [24576,25344) w2t | encHi 64MB | encLo 64MB
    const size_t NEED = 25344ull + 2ull * 64ull * 1024ull * 1024ull;

    hipLaunchKernelGGL(prep_weights, dim3(1), dim3(256), 0, stream, W0, W1, ws);

    if (ws_size >= NEED) {
        float* w2tG = (float*)((char*)d_ws + 24576);
        uint4* encHi = (uint4*)((char*)d_ws + 25344);
        uint4* encLo = encHi + (NPTS / 16) * 64;   // 4,194,304 uint4
        hipLaunchKernelGGL(prep_w2t, dim3(1), dim3(256), 0, stream, W2, w2tG);
        hipLaunchKernelGGL(ngp_encode, dim3(NPTS / 64), dim3(256), 0, stream,
                           xy, tables, encHi, encLo);
        hipLaunchKernelGGL(ngp_mlp, dim3(NPTS / 256), dim3(256), 0, stream,
                           ws, encHi, encLo, w2tG, out);
    } else {
        hipLaunchKernelGGL(ngp_mfma, dim3(NPTS / 256), dim3(256), 0, stream,
                           xy, tables, W2, ws, out);
    }
}